// Round 1
// baseline (218.799 us; speedup 1.0000x reference)
//
#include <hip/hip_runtime.h>

// MX (block=32) E4M3 quantize-dequantize, fp32 in/out.
// Each lane handles 4 consecutive floats (float4); 8 lanes = one 32-elem block.
// amax reduced across the 8-lane group via __shfl_xor (masks 1,2,4).
// All scales/quanta are powers of two -> arithmetic is bit-exact vs the
// numpy/jax fp32 reference (rintf == round-half-even == jnp.round).

__global__ __launch_bounds__(256) void mx_qdq_kernel(const float* __restrict__ x,
                                                     float* __restrict__ out,
                                                     int n4) {
    int idx = blockIdx.x * blockDim.x + threadIdx.x;
    if (idx >= n4) return;

    const float4* __restrict__ x4 = (const float4*)x;
    float4* __restrict__ o4 = (float4*)out;

    float4 v = x4[idx];

    // local amax over this lane's 4 elements
    float a = fmaxf(fmaxf(fabsf(v.x), fabsf(v.y)), fmaxf(fabsf(v.z), fabsf(v.w)));
    // reduce max across the 8-lane group that owns this 32-element block
    a = fmaxf(a, __shfl_xor(a, 1));
    a = fmaxf(a, __shfl_xor(a, 2));
    a = fmaxf(a, __shfl_xor(a, 4));

    float scale, inv_scale;
    if (a > 0.0f) {
        // floor(log2(a)) exactly: frexp gives a = f*2^e, f in [0.5,1) -> floor(log2(a)) = e-1
        int e;
        (void)frexpf(a, &e);
        int se = (e - 1) - 8;            // shared_exp = floor(log2(amax)) - ELEM_EMAX
        se = max(-127, min(127, se));    // E8M0 clip
        scale = ldexpf(1.0f, se);        // exact power of two
        inv_scale = ldexpf(1.0f, -se);   // exact; x*inv_scale == x/scale (both exact)
    } else {
        scale = 1.0f;
        inv_scale = 1.0f;
    }

    float r[4];
    float in[4] = {v.x, v.y, v.z, v.w};
#pragma unroll
    for (int k = 0; k < 4; ++k) {
        float xv = in[k];
        float val = xv * inv_scale;              // exact (power-of-two scale)
        float m = fminf(fabsf(val), 448.0f);     // saturate to E4M3 max
        float msafe = fmaxf(m, 0.015625f);       // 2^-6 (ELEM_EMIN) -> msafe is normal
        // e = floor(log2(msafe)) via exponent bits (msafe normal, >= 2^-6)
        int eb = (int)(__float_as_uint(msafe) >> 23);        // biased exponent, e = eb-127
        float inv_quantum = __uint_as_float((unsigned)(257 - eb) << 23); // 2^(3-e)
        float quantum     = __uint_as_float((unsigned)(eb - 3)  << 23); // 2^(e-3)
        float q = rintf(m * inv_quantum) * quantum;          // RNE, all steps exact
        r[k] = copysignf(q, xv) * scale;
    }

    float4 o;
    o.x = r[0]; o.y = r[1]; o.z = r[2]; o.w = r[3];
    o4[idx] = o;
}

extern "C" void kernel_launch(void* const* d_in, const int* in_sizes, int n_in,
                              void* d_out, int out_size, void* d_ws, size_t ws_size,
                              hipStream_t stream) {
    const float* x = (const float*)d_in[0];
    float* out = (float*)d_out;
    int n = in_sizes[0];          // 4096*8192, divisible by 32
    int n4 = n / 4;
    int block = 256;
    int grid = (n4 + block - 1) / block;
    mx_qdq_kernel<<<grid, block, 0, stream>>>(x, out, n4);
}

// Round 2
// 215.999 us; speedup vs baseline: 1.0130x; 1.0130x over previous
//
#include <hip/hip_runtime.h>

// MX (block=32) E4M3 quantize-dequantize, fp32 in/out.
// Each lane handles 4 consecutive floats (float4); 8 lanes = one 32-elem block.
// amax reduced across the 8-lane group via __shfl_xor (masks 1,2,4).
// All scales/quanta are powers of two -> arithmetic is bit-exact vs the
// numpy/jax fp32 reference (rintf == round-half-even == jnp.round).
//
// R1 changes vs R0:
//  - nontemporal load/store (input/output are streamed exactly once; keep
//    them out of L2 so the read+write stream behaves like the 6.6 TB/s fill)
//  - removed the (a > 0) branch: if amax == 0 every element is 0 and
//    0 * 2^se == 0 for any se, so the special-case scale=1 is unobservable.

typedef float v4f __attribute__((ext_vector_type(4)));

__global__ __launch_bounds__(256) void mx_qdq_kernel(const float* __restrict__ x,
                                                     float* __restrict__ out,
                                                     int n4) {
    int idx = blockIdx.x * blockDim.x + threadIdx.x;
    if (idx >= n4) return;

    const v4f* __restrict__ x4 = (const v4f*)x;
    v4f* __restrict__ o4 = (v4f*)out;

    v4f v = __builtin_nontemporal_load(&x4[idx]);

    // local amax over this lane's 4 elements
    float a = fmaxf(fmaxf(fabsf(v.x), fabsf(v.y)), fmaxf(fabsf(v.z), fabsf(v.w)));
    // reduce max across the 8-lane group that owns this 32-element block
    a = fmaxf(a, __shfl_xor(a, 1));
    a = fmaxf(a, __shfl_xor(a, 2));
    a = fmaxf(a, __shfl_xor(a, 4));

    // floor(log2(a)) exactly: frexp gives a = f*2^e, f in [0.5,1) -> floor(log2(a)) = e-1
    // (a==0 -> e=0 -> se=-9; harmless, all elements are 0 and 0*2^se==0)
    int e;
    (void)frexpf(a, &e);
    int se = (e - 1) - 8;            // shared_exp = floor(log2(amax)) - ELEM_EMAX
    se = max(-127, min(127, se));    // E8M0 clip
    float scale = ldexpf(1.0f, se);      // exact power of two
    float inv_scale = ldexpf(1.0f, -se); // exact; x*inv_scale == x/scale (both exact)

    float in[4] = {v.x, v.y, v.z, v.w};
    float r[4];
#pragma unroll
    for (int k = 0; k < 4; ++k) {
        float xv = in[k];
        float val = xv * inv_scale;              // exact (power-of-two scale)
        float m = fminf(fabsf(val), 448.0f);     // saturate to E4M3 max
        float msafe = fmaxf(m, 0.015625f);       // 2^-6 (ELEM_EMIN) -> msafe is normal
        // e = floor(log2(msafe)) via exponent bits (msafe normal, >= 2^-6)
        int eb = (int)(__float_as_uint(msafe) >> 23);                   // biased exponent
        float inv_quantum = __uint_as_float((unsigned)(257 - eb) << 23); // 2^(3-e)
        float quantum     = __uint_as_float((unsigned)(eb - 3)  << 23);  // 2^(e-3)
        float q = rintf(m * inv_quantum) * quantum;                      // RNE, exact
        r[k] = copysignf(q, xv) * scale;
    }

    v4f o;
    o.x = r[0]; o.y = r[1]; o.z = r[2]; o.w = r[3];
    __builtin_nontemporal_store(o, &o4[idx]);
}

extern "C" void kernel_launch(void* const* d_in, const int* in_sizes, int n_in,
                              void* d_out, int out_size, void* d_ws, size_t ws_size,
                              hipStream_t stream) {
    const float* x = (const float*)d_in[0];
    float* out = (float*)d_out;
    int n = in_sizes[0];          // 4096*8192, divisible by 32
    int n4 = n / 4;
    int block = 256;
    int grid = (n4 + block - 1) / block;
    mx_qdq_kernel<<<grid, block, 0, stream>>>(x, out, n4);
}